// Round 2
// baseline (701.852 us; speedup 1.0000x reference)
//
#include <hip/hip_runtime.h>
#include <hip/hip_bf16.h>
#include <cstdint>

// AttentionGNNLayer factored form:
//   per-node A=h@W1a+b1, B=h@W1b, q=h@Wq+bq, k=h@Wk+bk  (W1a=W1 rows 0..31, W1b=rows 32..63)
//   per-edge msg = relu(A[r]+B[s]+c*w1c) * sigmoid(q[s]·k[r]) aggregated by receiver.
// R2: device counting-sort edges by receiver (hist -> scan -> scatter payload {s,c}),
// then register aggregation per node (no output atomics), relu fused.
// Node features packed bf16 pairs: Ak[n][t]=(A|k<<16), Bq[n][t]=(B|q<<16) -> 128 B/side gathers.

#define NPB 8   // nodes per block-group (node kernels)

__device__ __forceinline__ float bf16lo(uint32_t u) {
    uint32_t b = (u & 0xFFFFu) << 16;
    float f; __builtin_memcpy(&f, &b, 4); return f;
}
__device__ __forceinline__ float bf16hi(uint32_t u) {
    uint32_t b = u & 0xFFFF0000u;
    float f; __builtin_memcpy(&f, &b, 4); return f;
}
__device__ __forceinline__ uint32_t pack_bf16(float lo, float hi) {
    __hip_bfloat16 l = __float2bfloat16(lo);
    __hip_bfloat16 h = __float2bfloat16(hi);
    uint16_t lb, hb;
    __builtin_memcpy(&lb, &l, 2);
    __builtin_memcpy(&hb, &h, 2);
    return (uint32_t)lb | ((uint32_t)hb << 16);
}

__global__ __launch_bounds__(256) void node_precompute(
    const float* __restrict__ h, const float* __restrict__ W1,
    const float* __restrict__ b1, const float* __restrict__ Wq,
    const float* __restrict__ bq, const float* __restrict__ Wk,
    const float* __restrict__ bk,
    uint32_t* __restrict__ Ak, uint32_t* __restrict__ Bq, int n_nodes)
{
    __shared__ float sW1a[1024], sW1b[1024], sWq[1024], sWk[1024];
    int tid = threadIdx.x;
    for (int i = tid; i < 1024; i += 256) {
        sW1a[i] = W1[i];          // W1 rows 0..31  (receiver part)
        sW1b[i] = W1[1024 + i];   // W1 rows 32..63 (sender part)
        sWq[i]  = Wq[i];
        sWk[i]  = Wk[i];
    }
    __syncthreads();
    int lane = tid & 31;
    int g    = tid >> 5;
    float bA = b1[lane], bQ = bq[lane], bK = bk[lane];

    for (int n0 = blockIdx.x * NPB; n0 < n_nodes; n0 += gridDim.x * NPB) {
        int n = n0 + g;
        if (n >= n_nodes) continue;
        float hv = h[n * 32 + lane];
        float accA = bA, accB = 0.f, accQ = bQ, accK = bK;
        #pragma unroll
        for (int j = 0; j < 32; ++j) {
            float hj = __shfl(hv, j, 32);   // broadcast within 32-lane group
            accA = fmaf(hj, sW1a[j * 32 + lane], accA);
            accB = fmaf(hj, sW1b[j * 32 + lane], accB);
            accQ = fmaf(hj, sWq [j * 32 + lane], accQ);
            accK = fmaf(hj, sWk [j * 32 + lane], accK);
        }
        Ak[n * 32 + lane] = pack_bf16(accA, accK);
        Bq[n * 32 + lane] = pack_bf16(accB, accQ);
    }
}

// ---- counting sort by receiver ----

__global__ __launch_bounds__(256) void hist_kernel(
    const int* __restrict__ receivers, uint32_t* __restrict__ counts, int n_edges)
{
    int i = (blockIdx.x * 256 + threadIdx.x) * 4;
    if (i + 3 < n_edges) {
        int4 r = *(const int4*)(receivers + i);
        atomicAdd(&counts[r.x], 1u);
        atomicAdd(&counts[r.y], 1u);
        atomicAdd(&counts[r.z], 1u);
        atomicAdd(&counts[r.w], 1u);
    } else {
        for (int j = i; j < n_edges && j < i + 4; ++j)
            atomicAdd(&counts[receivers[j]], 1u);
    }
}

__global__ __launch_bounds__(256) void scan_partial(
    const uint32_t* __restrict__ counts, uint32_t* __restrict__ blocksums, int n)
{
    __shared__ uint32_t lds[256];
    int t = threadIdx.x;
    int base = blockIdx.x * 1024 + t * 4;
    uint32_t s = 0;
    #pragma unroll
    for (int i = 0; i < 4; ++i) {
        int idx = base + i;
        if (idx < n) s += counts[idx];
    }
    lds[t] = s; __syncthreads();
    for (int off = 128; off > 0; off >>= 1) {
        if (t < off) lds[t] += lds[t + off];
        __syncthreads();
    }
    if (t == 0) blocksums[blockIdx.x] = lds[0];
}

__global__ void scan_blocksums(uint32_t* __restrict__ blocksums, int nb)
{
    if (threadIdx.x == 0 && blockIdx.x == 0) {
        uint32_t run = 0;
        for (int i = 0; i < nb; ++i) {
            uint32_t v = blocksums[i];
            blocksums[i] = run;     // exclusive
            run += v;
        }
    }
}

__global__ __launch_bounds__(256) void scan_final(
    const uint32_t* __restrict__ counts, const uint32_t* __restrict__ blocksums,
    uint32_t* __restrict__ start, uint32_t* __restrict__ cursor, int n)
{
    __shared__ uint32_t lds[256];
    int t = threadIdx.x;
    int base = blockIdx.x * 1024 + t * 4;
    uint32_t v[4]; uint32_t s = 0;
    #pragma unroll
    for (int i = 0; i < 4; ++i) {
        int idx = base + i;
        v[i] = (idx < n) ? counts[idx] : 0u;
        s += v[i];
    }
    lds[t] = s; __syncthreads();
    for (int off = 1; off < 256; off <<= 1) {
        uint32_t add = (t >= off) ? lds[t - off] : 0u;
        __syncthreads();
        lds[t] += add;
        __syncthreads();
    }
    uint32_t run = lds[t] - s + blocksums[blockIdx.x];  // exclusive prefix for this thread
    #pragma unroll
    for (int i = 0; i < 4; ++i) {
        int idx = base + i;
        if (idx < n) {
            start[idx]  = run;
            cursor[idx] = run;
            run += v[i];
        }
    }
}

__global__ __launch_bounds__(256) void scatter_kernel(
    const int* __restrict__ senders, const int* __restrict__ receivers,
    const float* __restrict__ couplings,
    uint32_t* __restrict__ cursor, uint2* __restrict__ payload,
    int n_edges, int e_half)
{
    int e = blockIdx.x * 256 + threadIdx.x;
    if (e >= n_edges) return;
    int r = receivers[e];
    uint32_t pos = atomicAdd(&cursor[r], 1u);
    float c = couplings[e < e_half ? e : e - e_half];
    payload[pos] = make_uint2((uint32_t)senders[e], __float_as_uint(c));
}

// ---- aggregation: one 32-lane group per node, register accumulate, fused relu ----

__global__ __launch_bounds__(256) void aggregate_kernel(
    const uint32_t* __restrict__ Ak, const uint32_t* __restrict__ Bq,
    const uint32_t* __restrict__ start, const uint32_t* __restrict__ counts,
    const uint2* __restrict__ payload, const float* __restrict__ W1,
    float* __restrict__ out, int n_nodes)
{
    int lane = threadIdx.x & 31;
    int g    = threadIdx.x >> 5;
    int n    = blockIdx.x * 8 + g;
    float w1c = W1[64 * 32 + lane];
    if (n >= n_nodes) return;

    uint32_t ak = Ak[(size_t)n * 32 + lane];
    float A = bf16lo(ak), k = bf16hi(ak);
    uint32_t cnt  = counts[n];
    uint32_t base = start[n];
    float acc = 0.f;

    if (cnt) {
        uint2 p = payload[base];                          // broadcast load
        uint32_t bqv = Bq[(size_t)p.x * 32 + lane];       // 128 B coalesced gather
        for (uint32_t j = 0; j < cnt; ++j) {
            uint2 pn = p; uint32_t bqn = bqv;
            if (j + 1 < cnt) {                            // prefetch next edge
                pn  = payload[base + j + 1];
                bqn = Bq[(size_t)pn.x * 32 + lane];
            }
            float c = __uint_as_float(p.y);
            float B = bf16lo(bqv), q = bf16hi(bqv);
            float msg = fmaxf(fmaf(c, w1c, A + B), 0.f);
            float d = q * k;
            #pragma unroll
            for (int m = 1; m < 32; m <<= 1)
                d += __shfl_xor(d, m, 64);                // masks <=16 stay in 32-half
            float sig = __fdividef(1.f, 1.f + __expf(-d));
            acc = fmaf(msg, sig, acc);
            p = pn; bqv = bqn;
        }
    }
    out[(size_t)n * 32 + lane] = fmaxf(acc, 0.f);
}

// ---- fallback (atomic path) if ws too small ----

__global__ __launch_bounds__(256) void edge_kernel_atomic(
    const uint32_t* __restrict__ Ak, const uint32_t* __restrict__ Bq,
    const int* __restrict__ senders, const int* __restrict__ receivers,
    const float* __restrict__ couplings, const float* __restrict__ W1,
    float* __restrict__ agg, int n_edges, int e_half)
{
    int lane = threadIdx.x & 31;
    int g    = threadIdx.x >> 5;
    int e    = blockIdx.x * 8 + g;
    float w1c = W1[64 * 32 + lane];
    if (e >= n_edges) return;
    int r = receivers[e];
    int s = senders[e];
    float c = couplings[e < e_half ? e : e - e_half];
    uint32_t ak = Ak[(size_t)r * 32 + lane];
    uint32_t bq = Bq[(size_t)s * 32 + lane];
    float A = bf16lo(ak), k = bf16hi(ak);
    float B = bf16lo(bq), q = bf16hi(bq);
    float msg = fmaxf(fmaf(c, w1c, A + B), 0.f);
    float p = q * k;
    #pragma unroll
    for (int m = 1; m < 32; m <<= 1)
        p += __shfl_xor(p, m, 64);
    float sig = __fdividef(1.f, 1.f + __expf(-p));
    atomicAdd(&agg[(size_t)r * 32 + lane], msg * sig);
}

__global__ __launch_bounds__(256) void relu_inplace(float4* __restrict__ out, int n4)
{
    int i = blockIdx.x * blockDim.x + threadIdx.x;
    if (i < n4) {
        float4 v = out[i];
        v.x = fmaxf(v.x, 0.f); v.y = fmaxf(v.y, 0.f);
        v.z = fmaxf(v.z, 0.f); v.w = fmaxf(v.w, 0.f);
        out[i] = v;
    }
}

extern "C" void kernel_launch(void* const* d_in, const int* in_sizes, int n_in,
                              void* d_out, int out_size, void* d_ws, size_t ws_size,
                              hipStream_t stream)
{
    const float* h         = (const float*)d_in[0];
    const float* couplings = (const float*)d_in[1];
    const float* W1        = (const float*)d_in[2];
    const float* b1        = (const float*)d_in[3];
    const float* Wq        = (const float*)d_in[4];
    const float* bq        = (const float*)d_in[5];
    const float* Wk        = (const float*)d_in[6];
    const float* bk        = (const float*)d_in[7];
    const int*   senders   = (const int*)d_in[8];
    const int*   receivers = (const int*)d_in[9];
    float* out = (float*)d_out;

    int n_nodes = in_sizes[0] / 32;
    int e_half  = in_sizes[1];
    int n_edges = in_sizes[8];

    size_t N32 = (size_t)n_nodes * 32;
    int nb = (n_nodes + 1023) / 1024;        // scan blocks

    // ws layout (all 256B-aligned)
    auto align256 = [](size_t x) { return (x + 255) & ~(size_t)255; };
    size_t off = 0;
    size_t akOff = off;       off = align256(off + N32 * 4);
    size_t bqOff = off;       off = align256(off + N32 * 4);
    size_t cntOff = off;      off = align256(off + (size_t)n_nodes * 4);
    size_t startOff = off;    off = align256(off + (size_t)n_nodes * 4);
    size_t curOff = off;      off = align256(off + (size_t)n_nodes * 4);
    size_t bsOff = off;       off = align256(off + (size_t)nb * 4);
    size_t plOff = off;       off = align256(off + (size_t)n_edges * 8);
    size_t needed = off;

    char* ws = (char*)d_ws;
    uint32_t* Ak     = (uint32_t*)(ws + akOff);
    uint32_t* Bq     = (uint32_t*)(ws + bqOff);

    node_precompute<<<1280, 256, 0, stream>>>(
        h, W1, b1, Wq, bq, Wk, bk, Ak, Bq, n_nodes);

    if (ws_size >= needed) {
        uint32_t* counts = (uint32_t*)(ws + cntOff);
        uint32_t* startp = (uint32_t*)(ws + startOff);
        uint32_t* cursor = (uint32_t*)(ws + curOff);
        uint32_t* bsums  = (uint32_t*)(ws + bsOff);
        uint2*    payload= (uint2*)   (ws + plOff);

        hipMemsetAsync(counts, 0, (size_t)n_nodes * 4, stream);
        hist_kernel<<<(n_edges + 1023) / 1024, 256, 0, stream>>>(receivers, counts, n_edges);
        scan_partial<<<nb, 256, 0, stream>>>(counts, bsums, n_nodes);
        scan_blocksums<<<1, 64, 0, stream>>>(bsums, nb);
        scan_final<<<nb, 256, 0, stream>>>(counts, bsums, startp, cursor, n_nodes);
        scatter_kernel<<<(n_edges + 255) / 256, 256, 0, stream>>>(
            senders, receivers, couplings, cursor, payload, n_edges, e_half);
        aggregate_kernel<<<(n_nodes + 7) / 8, 256, 0, stream>>>(
            Ak, Bq, startp, counts, payload, W1, out, n_nodes);
    } else {
        // fallback: atomic aggregation
        hipMemsetAsync(d_out, 0, (size_t)out_size * sizeof(float), stream);
        edge_kernel_atomic<<<(n_edges + 7) / 8, 256, 0, stream>>>(
            Ak, Bq, senders, receivers, couplings, W1, out, n_edges, e_half);
        int n4 = out_size / 4;
        relu_inplace<<<(n4 + 255) / 256, 256, 0, stream>>>((float4*)out, n4);
    }
}